// Round 5
// baseline (1570.655 us; speedup 1.0000x reference)
//
#include <hip/hip_runtime.h>
#include <hip/hip_bf16.h>

// RGCN segment MM, bucketized aggregate + fused GEMM:
//   out[d] = sum_r ( sum_{e: dst=d, et=r} feat[src[e]] ) @ W[r]
// Bucket = (dst>>7)*R + et  (6256 buckets). One bump-allocator scatter builds
// per-bucket record lists (rec = src | dl<<sbits). Fused kernel per 128-node
// block, per r: edge-parallel gather feat rows -> ds_add_f32 into fp32 LDS
// tile -> bf16 MFMA vs W[r] into resident accs -> single out store.

#define FEAT 128
#define LDW 132          // fp32 LDS row stride (132*4=528 B, 16B-aligned)
#define CAP 1024         // records per bucket (lambda~256, huge margin)

typedef __attribute__((ext_vector_type(8))) short short8;
typedef __attribute__((ext_vector_type(8))) __bf16 bf16x8;
typedef __attribute__((ext_vector_type(4))) float f32x4;

__device__ __forceinline__ unsigned f2bf(float x) {
    union { float f; unsigned u; } v; v.f = x;
    unsigned r = v.u + 0x7FFFu + ((v.u >> 16) & 1u);   // RNE
    return r >> 16;
}

// pack two fp32 -> bf16 pair (round-half-up), hi in upper 16
__device__ __forceinline__ unsigned pkbf(float lo, float hi) {
    unsigned ul = __float_as_uint(lo) + 0x8000u;
    unsigned uh = __float_as_uint(hi) + 0x8000u;
    return (uh & 0xffff0000u) | (ul >> 16);
}

// ---------------- conversions ----------------
__global__ void cvt_feat_kernel(const float* __restrict__ f,
                                ushort* __restrict__ o, int n8) {
    int i = blockIdx.x * blockDim.x + threadIdx.x;
    if (i >= n8) return;
    const float4* f4 = (const float4*)f;
    float4 a = f4[2 * i], b = f4[2 * i + 1];
    union { ushort u[8]; int4 v; } pk;
    pk.u[0] = f2bf(a.x); pk.u[1] = f2bf(a.y); pk.u[2] = f2bf(a.z); pk.u[3] = f2bf(a.w);
    pk.u[4] = f2bf(b.x); pk.u[5] = f2bf(b.y); pk.u[6] = f2bf(b.z); pk.u[7] = f2bf(b.w);
    ((int4*)o)[i] = pk.v;
}

// W[r][k][n] fp32 -> Wt[n][r*128+k] bf16 (K-stacked, n-major)
__global__ void cvt_w_kernel(const float* __restrict__ w,
                             ushort* __restrict__ wt, int total, int KW) {
    int i = blockIdx.x * blockDim.x + threadIdx.x;
    if (i >= total) return;
    int n = i / KW;
    int rk = i - n * KW;
    int r = rk >> 7, k = rk & 127;
    wt[i] = (ushort)f2bf(w[(r << 14) + (k << 7) + n]);
}

// ---------------- bucketize edges (bump allocator, no sort) ----------------
__global__ void scatter_kernel(const int* __restrict__ dst,
                               const int* __restrict__ et,
                               const int* __restrict__ src, int E, int R,
                               int sbits, int* __restrict__ cursor,
                               int* __restrict__ recs) {
    int i = blockIdx.x * blockDim.x + threadIdx.x;
    int stride = gridDim.x * blockDim.x;
    for (; i < E; i += stride) {
        int d = dst[i];
        int b = (d >> 7) * R + et[i];
        int p = atomicAdd(&cursor[b], 1);
        if (p < CAP) recs[(size_t)b * CAP + p] = src[i] | ((d & 127) << sbits);
    }
}

// ---------------- fused aggregate + GEMM ----------------
// Block = 128 dst nodes, 4 waves, 2 blocks/CU (66KB LDS). Per r: zero fp32
// tile, edge-parallel gather+ds_add_f32, then MFMA from the tile.
__global__ __launch_bounds__(256, 2)
void fused_kernel(const ushort* __restrict__ featb,
                  const ushort* __restrict__ wtb,
                  const int* __restrict__ recs,
                  const int* __restrict__ cursor,
                  float* __restrict__ out, int N, int R, int KW, int sbits) {
    __shared__ __align__(16) float Sf[128 * LDW];   // 67584 B
    int t = threadIdx.x, wid = t >> 6, lane = t & 63;
    int eq = lane >> 4, c = lane & 15;     // quad id / col-chunk (gather)
    int lm = lane & 15, lq = lane >> 4;    // MFMA fragment coords
    int blk = blockIdx.x, base = blk * 128;
    int mq = (wid >> 1) * 64, nq = (wid & 1) * 64;
    int qid = wid * 4 + eq;                // 0..15
    int smask = (1 << sbits) - 1;

    f32x4 acc[16];
    #pragma unroll
    for (int i = 0; i < 16; i++) acc[i] = (f32x4){0.f, 0.f, 0.f, 0.f};

    for (int r = 0; r < R; r++) {
        int bkt = blk * R + r;
        int ecnt = cursor[bkt];
        if (ecnt <= 0) continue;           // block-uniform
        if (ecnt > CAP) ecnt = CAP;

        // zero the fp32 tile
        #pragma unroll 4
        for (int i = t; i < 128 * LDW / 4; i += 256)
            ((float4*)Sf)[i] = (float4){0.f, 0.f, 0.f, 0.f};
        __syncthreads();

        // edge-parallel gather + LDS fp32 atomic accumulate
        const int* rb = recs + (size_t)bkt * CAP;
        for (int e0 = 0; e0 < ecnt; e0 += 64) {
            int rv[4]; uint4 v[4];
            #pragma unroll
            for (int u = 0; u < 4; u++) {
                int idx = e0 + u * 16 + qid;
                rv[u] = (idx < ecnt) ? rb[idx] : -1;
            }
            #pragma unroll
            for (int u = 0; u < 4; u++)
                if (rv[u] >= 0)
                    v[u] = *(const uint4*)(featb +
                           (size_t)(rv[u] & smask) * FEAT + c * 8);
            #pragma unroll
            for (int u = 0; u < 4; u++) {
                if (rv[u] >= 0) {
                    int dl = (rv[u] >> sbits) & 127;
                    float* sp = &Sf[dl * LDW + c * 8];
                    atomicAdd(sp + 0, __uint_as_float(v[u].x << 16));
                    atomicAdd(sp + 1, __uint_as_float(v[u].x & 0xffff0000u));
                    atomicAdd(sp + 2, __uint_as_float(v[u].y << 16));
                    atomicAdd(sp + 3, __uint_as_float(v[u].y & 0xffff0000u));
                    atomicAdd(sp + 4, __uint_as_float(v[u].z << 16));
                    atomicAdd(sp + 5, __uint_as_float(v[u].z & 0xffff0000u));
                    atomicAdd(sp + 6, __uint_as_float(v[u].w << 16));
                    atomicAdd(sp + 7, __uint_as_float(v[u].w & 0xffff0000u));
                }
            }
        }
        __syncthreads();

        // acc += S_r @ W[r]; A from fp32 LDS tile (pack to bf16), B from L2
        const ushort* bp = wtb + (size_t)(nq + lm) * KW + r * FEAT;
        #pragma unroll
        for (int ks = 0; ks < 4; ks++) {
            int kof = ks * 32 + lq * 8;
            short8 af[4], bfg[4];
            #pragma unroll
            for (int tm = 0; tm < 4; tm++) {
                const float* sp = &Sf[(mq + tm * 16 + lm) * LDW + kof];
                f32x4 x = *(const f32x4*)sp;
                f32x4 y = *(const f32x4*)(sp + 4);
                union { unsigned u[4]; short8 s; } pk;
                pk.u[0] = pkbf(x[0], x[1]);
                pk.u[1] = pkbf(x[2], x[3]);
                pk.u[2] = pkbf(y[0], y[1]);
                pk.u[3] = pkbf(y[2], y[3]);
                af[tm] = pk.s;
            }
            #pragma unroll
            for (int tn = 0; tn < 4; tn++)
                bfg[tn] = *(const short8*)(bp + (size_t)(tn * 16) * KW + kof);
            #pragma unroll
            for (int tm = 0; tm < 4; tm++)
                #pragma unroll
                for (int tn = 0; tn < 4; tn++)
                    acc[tm * 4 + tn] = __builtin_amdgcn_mfma_f32_16x16x32_bf16(
                        __builtin_bit_cast(bf16x8, af[tm]),
                        __builtin_bit_cast(bf16x8, bfg[tn]),
                        acc[tm * 4 + tn], 0, 0, 0);
        }
        __syncthreads();
    }

    // epilogue: single store of the 128x128 out tile
    #pragma unroll
    for (int tm = 0; tm < 4; tm++) {
        #pragma unroll
        for (int i = 0; i < 4; i++) {
            int row = base + mq + tm * 16 + lq * 4 + i;
            if (row < N) {
                float* op = out + (size_t)row * FEAT + nq + lm;
                #pragma unroll
                for (int tn = 0; tn < 4; tn++) op[tn * 16] = acc[tm * 4 + tn][i];
            }
        }
    }
}

static inline size_t al256(size_t x) { return (x + 255) & ~(size_t)255; }

extern "C" void kernel_launch(void* const* d_in, const int* in_sizes, int n_in,
                              void* d_out, int out_size, void* d_ws,
                              size_t ws_size, hipStream_t stream) {
    const float* feat = (const float*)d_in[0];
    const float* weight = (const float*)d_in[1];
    const int* src = (const int*)d_in[2];
    const int* dst = (const int*)d_in[3];
    const int* et = (const int*)d_in[4];

    int nfeat = in_sizes[0];
    int N = nfeat / FEAT;                    // 100000
    int R = in_sizes[1] / (FEAT * FEAT);     // 8
    int E = in_sizes[2];                     // 1.6M
    int Npad = ((N + 127) / 128) * 128;
    int nblk = Npad / 128;                   // 782
    int NB = nblk * R;                       // 6256 buckets
    int KW = R * FEAT;                       // 1024
    float* out = (float*)d_out;

    int sbits = 1;
    while ((1 << sbits) < N) sbits++;        // 17 for N=100000

    // ---- workspace layout (~54 MB) ----
    char* ws = (char*)d_ws;
    size_t o = 0;
    size_t cur_o  = o; o += al256((size_t)NB * 4);
    size_t recs_o = o; o += al256((size_t)NB * CAP * 4);
    size_t wtb_o  = o; o += al256((size_t)R * FEAT * FEAT * 2);
    size_t featb_o = o;

    int* cursor = (int*)(ws + cur_o);
    int* recs   = (int*)(ws + recs_o);
    ushort* wtb   = (ushort*)(ws + wtb_o);
    ushort* featb = (ushort*)(ws + featb_o);

    hipMemsetAsync(cursor, 0, (size_t)NB * 4, stream);

    int wtotal = R * FEAT * FEAT;
    cvt_w_kernel<<<(wtotal + 255) / 256, 256, 0, stream>>>(weight, wtb, wtotal, KW);
    int n8 = nfeat / 8;
    cvt_feat_kernel<<<(n8 + 255) / 256, 256, 0, stream>>>(feat, featb, n8);

    scatter_kernel<<<512, 256, 0, stream>>>(dst, et, src, E, R, sbits,
                                            cursor, recs);

    fused_kernel<<<nblk, 256, 0, stream>>>(featb, wtb, recs, cursor,
                                           out, N, R, KW, sbits);
}

// Round 6
// 511.534 us; speedup vs baseline: 3.0705x; 3.0705x over previous
//
#include <hip/hip_runtime.h>
#include <hip/hip_bf16.h>

// RGCN segment MM:  out[d] = sum_r ( sum_{e: dst=d, et=r} feat[src[e]] ) @ W[r]
// Bucket = (dst>>7)*R + et (6256 buckets) built by one bump-allocator scatter
// (rec = src | dl<<sbits). Fused kernel, per (block of 128 dst, r):
//   1) in-LDS counting sort of the bucket by dl (run bounds = bin offsets)
//   2) per 128-edge chunk: edge-parallel 16B gathers staged into LDS
//   3) owner (quad-per-node) reduce from LDS into registers  -> bf16 Ssm
//   4) MFMA Ssm @ W[r] into resident fp32 accumulators; single out store.
// Zero atomics on float data; the only atomics are 2 int-incs per edge.

#define FEAT 128
#define LDG 136          // staged-G row stride (bf16)
#define LDSS 136         // Ssm row stride (bf16)
#define CAP 1024         // records per bucket (lambda~256)
#define CHUNK 128

typedef __attribute__((ext_vector_type(8))) short short8;
typedef __attribute__((ext_vector_type(8))) __bf16 bf16x8;
typedef __attribute__((ext_vector_type(4))) float f32x4;

__device__ __forceinline__ unsigned f2bf(float x) {
    union { float f; unsigned u; } v; v.f = x;
    unsigned r = v.u + 0x7FFFu + ((v.u >> 16) & 1u);   // RNE
    return r >> 16;
}

// ---------------- conversions ----------------
__global__ void cvt_feat_kernel(const float* __restrict__ f,
                                ushort* __restrict__ o, int n8) {
    int i = blockIdx.x * blockDim.x + threadIdx.x;
    if (i >= n8) return;
    const float4* f4 = (const float4*)f;
    float4 a = f4[2 * i], b = f4[2 * i + 1];
    union { ushort u[8]; int4 v; } pk;
    pk.u[0] = f2bf(a.x); pk.u[1] = f2bf(a.y); pk.u[2] = f2bf(a.z); pk.u[3] = f2bf(a.w);
    pk.u[4] = f2bf(b.x); pk.u[5] = f2bf(b.y); pk.u[6] = f2bf(b.z); pk.u[7] = f2bf(b.w);
    ((int4*)o)[i] = pk.v;
}

// W[r][k][n] fp32 -> Wt[n][r*128+k] bf16 (K-stacked, n-major)
__global__ void cvt_w_kernel(const float* __restrict__ w,
                             ushort* __restrict__ wt, int total, int KW) {
    int i = blockIdx.x * blockDim.x + threadIdx.x;
    if (i >= total) return;
    int n = i / KW;
    int rk = i - n * KW;
    int r = rk >> 7, k = rk & 127;
    wt[i] = (ushort)f2bf(w[(r << 14) + (k << 7) + n]);
}

// ---------------- bucketize edges (bump allocator) ----------------
__global__ void scatter_kernel(const int* __restrict__ dst,
                               const int* __restrict__ et,
                               const int* __restrict__ src, int E, int R,
                               int sbits, int* __restrict__ cursor,
                               int* __restrict__ recs) {
    int i = blockIdx.x * blockDim.x + threadIdx.x;
    int stride = gridDim.x * blockDim.x;
    for (; i < E; i += stride) {
        int d = dst[i];
        int b = (d >> 7) * R + et[i];
        int p = atomicAdd(&cursor[b], 1);
        if (p < CAP) recs[(size_t)b * CAP + p] = src[i] | ((d & 127) << sbits);
    }
}

// ---------------- fused aggregate + GEMM ----------------
__global__ __launch_bounds__(256, 2)
void fused_kernel(const ushort* __restrict__ featb,
                  const ushort* __restrict__ wtb,
                  const int* __restrict__ recs,
                  const int* __restrict__ cursor,
                  float* __restrict__ out, int N, int R, int KW, int sbits) {
    __shared__ int unsrt[CAP];
    __shared__ int srt[CAP];
    __shared__ int bins[128];
    __shared__ int binOff[129];
    __shared__ int binCur[128];
    __shared__ __align__(16) ushort G[CHUNK * LDG];    // 34816 B
    __shared__ __align__(16) ushort Ssm[128 * LDSS];   // 34816 B

    int t = threadIdx.x;
    int qid = t >> 4, c = t & 15;          // quad (node/edge slot) / col chunk
    int lane = t & 63, wid = t >> 6;
    int lm = lane & 15, lq = lane >> 4;    // MFMA fragment coords
    int blk = blockIdx.x, base = blk * 128;
    int mq = (wid >> 1) * 64, nq = (wid & 1) * 64;
    int smask = (1 << sbits) - 1;

    f32x4 acc[16];
    #pragma unroll
    for (int i = 0; i < 16; i++) acc[i] = (f32x4){0.f, 0.f, 0.f, 0.f};

    for (int r = 0; r < R; r++) {
        int bkt = blk * R + r;
        int ecnt = cursor[bkt];
        if (ecnt <= 0) continue;           // block-uniform
        if (ecnt > CAP) ecnt = CAP;

        // ---- 1) in-LDS counting sort by dl ----
        if (t < 128) bins[t] = 0;
        __syncthreads();
        const int* rb = recs + (size_t)bkt * CAP;
        for (int i = t; i < ecnt; i += 256) {
            int rc = rb[i];
            unsrt[i] = rc;
            atomicAdd(&bins[(rc >> sbits) & 127], 1);
        }
        __syncthreads();
        if (t < 64) {                      // exclusive scan of 128 bins
            int b0 = bins[2 * t], b1 = bins[2 * t + 1];
            int s = b0 + b1, x = s;
            for (int o = 1; o < 64; o <<= 1) {
                int y = __shfl_up(x, o, 64);
                if (t >= o) x += y;
            }
            int ex = x - s;
            binOff[2 * t] = ex;     binOff[2 * t + 1] = ex + b0;
            binCur[2 * t] = ex;     binCur[2 * t + 1] = ex + b0;
            if (t == 63) binOff[128] = ex + s;
        }
        __syncthreads();
        for (int i = t; i < ecnt; i += 256) {
            int rc = unsrt[i];
            int p = atomicAdd(&binCur[(rc >> sbits) & 127], 1);
            srt[p] = rc;
        }

        // hoist this slot's run bounds (nodes g*16+qid, g=0..7)
        int bo0[8], bo1[8];
        float S[8][8];
        #pragma unroll
        for (int g = 0; g < 8; g++)
            #pragma unroll
            for (int k = 0; k < 8; k++) S[g][k] = 0.f;
        __syncthreads();
        #pragma unroll
        for (int g = 0; g < 8; g++) {
            int n = g * 16 + qid;
            bo0[g] = binOff[n];
            bo1[g] = binOff[n + 1];
        }

        // ---- 2+3) chunk loop: gather-stage then owner-reduce ----
        for (int c0 = 0; c0 < ecnt; c0 += CHUNK) {
            int cc = ecnt - c0; if (cc > CHUNK) cc = CHUNK;
            int rcv[8]; uint4 gvv[8];
            #pragma unroll
            for (int p = 0; p < 8; p++) {
                int jl = p * 16 + qid;
                rcv[p] = (jl < cc) ? srt[c0 + jl] : -1;
            }
            #pragma unroll
            for (int p = 0; p < 8; p++)
                if (rcv[p] >= 0)
                    gvv[p] = *(const uint4*)(featb +
                             (size_t)(rcv[p] & smask) * FEAT + c * 8);
            #pragma unroll
            for (int p = 0; p < 8; p++)
                if (rcv[p] >= 0)
                    *(uint4*)&G[(p * 16 + qid) * LDG + c * 8] = gvv[p];
            __syncthreads();

            #pragma unroll
            for (int g = 0; g < 8; g++) {
                int lo = bo0[g] < c0 ? c0 : bo0[g];
                int hiB = c0 + cc;
                int hi = bo1[g] < hiB ? bo1[g] : hiB;
                for (int e = lo; e < hi; e++) {
                    uint4 v = *(const uint4*)&G[(e - c0) * LDG + c * 8];
                    S[g][0] += __uint_as_float(v.x << 16);
                    S[g][1] += __uint_as_float(v.x & 0xffff0000u);
                    S[g][2] += __uint_as_float(v.y << 16);
                    S[g][3] += __uint_as_float(v.y & 0xffff0000u);
                    S[g][4] += __uint_as_float(v.z << 16);
                    S[g][5] += __uint_as_float(v.z & 0xffff0000u);
                    S[g][6] += __uint_as_float(v.w << 16);
                    S[g][7] += __uint_as_float(v.w & 0xffff0000u);
                }
            }
            __syncthreads();
        }

        // ---- pack S -> Ssm (bf16) ----
        #pragma unroll
        for (int g = 0; g < 8; g++) {
            int n = g * 16 + qid;
            uint4 pk;
            pk.x = f2bf(S[g][0]) | (f2bf(S[g][1]) << 16);
            pk.y = f2bf(S[g][2]) | (f2bf(S[g][3]) << 16);
            pk.z = f2bf(S[g][4]) | (f2bf(S[g][5]) << 16);
            pk.w = f2bf(S[g][6]) | (f2bf(S[g][7]) << 16);
            *(uint4*)&Ssm[n * LDSS + c * 8] = pk;
        }
        __syncthreads();

        // ---- 4) acc += Ssm @ W[r]  (B direct from L2-hot wtb) ----
        const ushort* bp = wtb + (size_t)(nq + lm) * KW + r * FEAT;
        #pragma unroll
        for (int ks = 0; ks < 4; ks++) {
            int kof = ks * 32 + lq * 8;
            short8 af[4], bfg[4];
            #pragma unroll
            for (int tm = 0; tm < 4; tm++)
                af[tm] = *(const short8*)&Ssm[(mq + tm * 16 + lm) * LDSS + kof];
            #pragma unroll
            for (int tn = 0; tn < 4; tn++)
                bfg[tn] = *(const short8*)(bp + (size_t)(tn * 16) * KW + kof);
            #pragma unroll
            for (int tm = 0; tm < 4; tm++)
                #pragma unroll
                for (int tn = 0; tn < 4; tn++)
                    acc[tm * 4 + tn] = __builtin_amdgcn_mfma_f32_16x16x32_bf16(
                        __builtin_bit_cast(bf16x8, af[tm]),
                        __builtin_bit_cast(bf16x8, bfg[tn]),
                        acc[tm * 4 + tn], 0, 0, 0);
        }
        __syncthreads();
    }

    // ---- epilogue: single store of the 128x128 out tile ----
    #pragma unroll
    for (int tm = 0; tm < 4; tm++) {
        #pragma unroll
        for (int i = 0; i < 4; i++) {
            int row = base + mq + tm * 16 + lq * 4 + i;
            if (row < N) {
                float* op = out + (size_t)row * FEAT + nq + lm;
                #pragma unroll
                for (int tn = 0; tn < 4; tn++) op[tn * 16] = acc[tm * 4 + tn][i];
            }
        }
    }
}

static inline size_t al256(size_t x) { return (x + 255) & ~(size_t)255; }

extern "C" void kernel_launch(void* const* d_in, const int* in_sizes, int n_in,
                              void* d_out, int out_size, void* d_ws,
                              size_t ws_size, hipStream_t stream) {
    const float* feat = (const float*)d_in[0];
    const float* weight = (const float*)d_in[1];
    const int* src = (const int*)d_in[2];
    const int* dst = (const int*)d_in[3];
    const int* et = (const int*)d_in[4];

    int nfeat = in_sizes[0];
    int N = nfeat / FEAT;                    // 100000
    int R = in_sizes[1] / (FEAT * FEAT);     // 8
    int E = in_sizes[2];                     // 1.6M
    int Npad = ((N + 127) / 128) * 128;
    int nblk = Npad / 128;                   // 782
    int NB = nblk * R;                       // 6256 buckets
    int KW = R * FEAT;                       // 1024
    float* out = (float*)d_out;

    int sbits = 1;
    while ((1 << sbits) < N) sbits++;        // 17 for N=100000

    // ---- workspace layout (~54 MB) ----
    char* ws = (char*)d_ws;
    size_t o = 0;
    size_t cur_o  = o; o += al256((size_t)NB * 4);
    size_t recs_o = o; o += al256((size_t)NB * CAP * 4);
    size_t wtb_o  = o; o += al256((size_t)R * FEAT * FEAT * 2);
    size_t featb_o = o;

    int* cursor = (int*)(ws + cur_o);
    int* recs   = (int*)(ws + recs_o);
    ushort* wtb   = (ushort*)(ws + wtb_o);
    ushort* featb = (ushort*)(ws + featb_o);

    hipMemsetAsync(cursor, 0, (size_t)NB * 4, stream);

    int wtotal = R * FEAT * FEAT;
    cvt_w_kernel<<<(wtotal + 255) / 256, 256, 0, stream>>>(weight, wtb, wtotal, KW);
    int n8 = nfeat / 8;
    cvt_feat_kernel<<<(n8 + 255) / 256, 256, 0, stream>>>(feat, featb, n8);

    scatter_kernel<<<512, 256, 0, stream>>>(dst, et, src, E, R, sbits,
                                            cursor, recs);

    fused_kernel<<<nblk, 256, 0, stream>>>(featb, wtb, recs, cursor,
                                           out, N, R, KW, sbits);
}